// Round 21
// baseline (382.375 us; speedup 1.0000x reference)
//
#include <hip/hip_runtime.h>
#include <hip/hip_bf16.h>
#include <math.h>

#define B_ 8
#define S_ 1024
#define D_ 1024
#define H_ 16
#define DH_ 64
#define FFN_ 4096
#define NEG_ (-1e9f)
#define EPS_ 1e-5f

typedef float f32x4 __attribute__((ext_vector_type(4)));
typedef short bf16x8 __attribute__((ext_vector_type(8)));

__device__ __forceinline__ ushort f2b(float f) {
  __hip_bfloat16 h = __float2bfloat16(f);  // RNE
  return *reinterpret_cast<ushort*>(&h);
}
__device__ __forceinline__ float b2f(ushort u) {
  return __uint_as_float((unsigned)u << 16);
}

__device__ __forceinline__ void gload16(const void* g, void* l) {
  auto* lp = (__attribute__((address_space(3))) unsigned*)(uintptr_t)(l);
  __builtin_amdgcn_global_load_lds(
      (const __attribute__((address_space(1))) unsigned*)g, lp, 16, 0, 0);
}

// XOR swizzle for [*][64]-ushort LDS tiles (128B row stride)
__device__ __forceinline__ void* swz_ptr(void* base, int row, int col) {
  int byte = (row << 7) + (col << 1);
  byte ^= (row & 7) << 4;
  return (char*)base + byte;
}
// XOR swizzle for [*][128]-ushort LDS tiles (256B row stride)
__device__ __forceinline__ void* swz256(void* base, int row, int col) {
  int byte = (row << 8) + (col << 1);
  byte ^= (row & 7) << 4;
  return (char*)base + byte;
}

#define BARR asm volatile("s_barrier" ::: "memory")
#define LGKM0                                         \
  do {                                                \
    asm volatile("s_waitcnt lgkmcnt(0)" ::: "memory"); \
    __builtin_amdgcn_sched_barrier(0);                \
  } while (0)

// ---------------------------------------------------------------------------
// merged prep: cast x/Wo/W1/W2 to bf16 + pack qkv weights transposed.
// ---------------------------------------------------------------------------
__global__ __launch_bounds__(256) void prep_k(
    const float* __restrict__ x, const float* __restrict__ Wq,
    const float* __restrict__ Wk, const float* __restrict__ Wv,
    const float* __restrict__ Wo, const float* __restrict__ W1,
    const float* __restrict__ W2, ushort* __restrict__ xbf,
    ushort* __restrict__ qkvw, ushort* __restrict__ wob,
    ushort* __restrict__ w1b, ushort* __restrict__ w2b) {
  const int blk = blockIdx.x, t = threadIdx.x;
  if (blk < 8192) {  // x: 2M float4
    int i = blk * 256 + t;
    float4 v = ((const float4*)x)[i];
    ushort4 o;
    o.x = f2b(v.x); o.y = f2b(v.y); o.z = f2b(v.z); o.w = f2b(v.w);
    ((ushort4*)xbf)[i] = o;
  } else if (blk < 8192 + 12288) {  // qkvT pack: 3M scalars, k fastest
    int idx = (blk - 8192) * 256 + t;
    int k = idx & 1023, e = (idx >> 10) & 63;
    int h = (idx >> 16) & 15, which = idx >> 20;
    const float* W = (which == 0) ? Wq : (which == 1 ? Wk : Wv);
    float v = W[((size_t)h * D_ + k) * DH_ + e];
    qkvw[((size_t)which * 1024 + h * 64 + e) * 1024 + k] = f2b(v);
  } else if (blk < 8192 + 12288 + 1024) {  // Wo: 256K float4
    int i = (blk - 8192 - 12288) * 256 + t;
    float4 v = ((const float4*)Wo)[i];
    ushort4 o;
    o.x = f2b(v.x); o.y = f2b(v.y); o.z = f2b(v.z); o.w = f2b(v.w);
    ((ushort4*)wob)[i] = o;
  } else if (blk < 8192 + 12288 + 1024 + 4096) {  // W1: 1M float4
    int i = (blk - 8192 - 12288 - 1024) * 256 + t;
    float4 v = ((const float4*)W1)[i];
    ushort4 o;
    o.x = f2b(v.x); o.y = f2b(v.y); o.z = f2b(v.z); o.w = f2b(v.w);
    ((ushort4*)w1b)[i] = o;
  } else {  // W2: 1M float4
    int i = (blk - 8192 - 12288 - 1024 - 4096) * 256 + t;
    float4 v = ((const float4*)W2)[i];
    ushort4 o;
    o.x = f2b(v.x); o.y = f2b(v.y); o.z = f2b(v.z); o.w = f2b(v.w);
    ((ushort4*)w2b)[i] = o;
  }
}

// ---------------------------------------------------------------------------
// 8-phase 256x256 bf16 MFMA GEMM (T2+T3+T4+T5), K-half staging (R14-proven).
// SPLITK=1: block-half kh2 -> C / C2. VSPLIT (QKV): C2 slot is vT.
// ---------------------------------------------------------------------------
template <int BIAS, int RELU, int VSPLIT, int SPLITK>
__global__ __launch_bounds__(512, 2) void gemm8p(
    const ushort* __restrict__ A, const ushort* __restrict__ Bt,
    const float* __restrict__ bias, ushort* __restrict__ C,
    ushort* __restrict__ C2, int M, int N, int K) {
  __shared__ ushort lds[2][2][2][256 * 32];  // [buf][A/B][kh][row][k] 128KiB
  int bid = blockIdx.x;
  int nwg = gridDim.x;
  int kh2 = 0;
  if (SPLITK) {
    int hw = nwg >> 1;
    if (bid >= hw) { kh2 = 1; bid -= hw; }
    nwg = hw;
  }
  const int nbn = N >> 8;
  const int cpx = nwg >> 3;
  const int swz = (bid & 7) * cpx + (bid >> 3);  // XCD swizzle (nwg%8==0)
  const int bm = swz / nbn, bn = swz % nbn;
  const int Keff = SPLITK ? (K >> 1) : K;

  const int t = threadIdx.x;
  const int lane = t & 63, lr = lane & 15, lg = lane >> 4;
  const int wid = t >> 6, wr = wid >> 2, wc = wid & 3;  // 2M x 4N
  const size_t Kb = (size_t)K * 2;  // full row stride
  const char* Ab = (const char*)A + ((size_t)(bm << 8)) * Kb +
                   (size_t)kh2 * Keff * 2;
  const char* Bb = (const char*)Bt + ((size_t)(bn << 8)) * Kb +
                   (size_t)kh2 * Keff * 2;
  const int NT = Keff >> 6;
  const int niter = NT >> 1;

  const int g0row = t >> 2;
  const int gsi = (t & 3) ^ ((g0row >> 2) & 3);  // pre-swizzled src granule
  auto STG = [&](int mat, int kh, int kt) {
    char* base = (char*)&lds[kt & 1][mat][kh][0];
    const char* gsrc = mat ? Bb : Ab;
#pragma unroll
    for (int j = 0; j < 2; j++) {
      int row = g0row + j * 128;
      const char* src = gsrc + (size_t)row * Kb +
                        (size_t)(kt * 64 + kh * 32) * 2 + gsi * 16;
      gload16(src, base + t * 16 + j * 8192);
    }
  };

  const int rg = (lg ^ ((lr >> 2) & 3)) << 3;  // swizzled k-granule (ushort)
#define LDA(DST, BUF, KH, QM)                                            \
  _Pragma("unroll") for (int mm = 0; mm < 4; mm++) {                     \
    int row = wr * 128 + (QM)*64 + mm * 16 + lr;                         \
    DST[mm] = *(const bf16x8*)&lds[BUF][0][KH][row * 32 + rg];           \
  }
#define LDB(DST, BUF, KH)                                                \
  _Pragma("unroll") for (int nn = 0; nn < 4; nn++) {                     \
    int row = wc * 64 + nn * 16 + lr;                                    \
    DST[nn] = *(const bf16x8*)&lds[BUF][1][KH][row * 32 + rg];           \
  }
#define MFQ(QM, AS, BS)                                                  \
  do {                                                                   \
    __builtin_amdgcn_s_setprio(1);                                       \
    _Pragma("unroll") for (int mm = 0; mm < 4; mm++)                     \
        _Pragma("unroll") for (int nn = 0; nn < 4; nn++)                 \
            acc[(QM)*4 + mm][nn] = __builtin_amdgcn_mfma_f32_16x16x32_bf16( \
                AS[mm], BS[nn], acc[(QM)*4 + mm][nn], 0, 0, 0);          \
    __builtin_amdgcn_s_setprio(0);                                       \
  } while (0)

  f32x4 acc[8][4] = {};
  bf16x8 aS0[4], aS1[4], bS0[4], bS1[4];

  STG(0, 0, 0); STG(1, 0, 0); STG(0, 1, 0); STG(1, 1, 0);
  STG(0, 0, 1); STG(1, 0, 1);
  asm volatile("s_waitcnt vmcnt(4)" ::: "memory");
  BARR;

  for (int i = 0; i < niter; i++) {
    const int c1 = 2 * i + 1, c2 = 2 * i + 2, c3 = 2 * i + 3;
    LDA(aS0, 0, 0, 0); LDB(bS0, 0, 0); STG(0, 1, c1);
    BARR; LGKM0; MFQ(0, aS0, bS0); BARR;
    LDA(aS1, 0, 0, 1); STG(1, 1, c1);
    BARR; LGKM0; MFQ(1, aS1, bS0); BARR;
    LDA(aS0, 0, 1, 0); LDB(bS1, 0, 1);
    if (c2 < NT) STG(0, 0, c2);
    BARR; LGKM0; MFQ(0, aS0, bS1); BARR;
    LDA(aS1, 0, 1, 1);
    if (c2 < NT) STG(1, 0, c2);
    BARR; LGKM0; MFQ(1, aS1, bS1);
    if (i + 1 < niter)
      asm volatile("s_waitcnt vmcnt(4)" ::: "memory");
    else
      asm volatile("s_waitcnt vmcnt(0)" ::: "memory");
    BARR;
    LDA(aS0, 1, 0, 0); LDB(bS0, 1, 0);
    if (c2 < NT) STG(0, 1, c2);
    BARR; LGKM0; MFQ(0, aS0, bS0); BARR;
    LDA(aS1, 1, 0, 1);
    if (c2 < NT) STG(1, 1, c2);
    BARR; LGKM0; MFQ(1, aS1, bS0); BARR;
    LDA(aS0, 1, 1, 0); LDB(bS1, 1, 1);
    if (c3 < NT) STG(0, 0, c3);
    BARR; LGKM0; MFQ(0, aS0, bS1); BARR;
    LDA(aS1, 1, 1, 1);
    if (c3 < NT) STG(1, 0, c3);
    BARR; LGKM0; MFQ(1, aS1, bS1);
    asm volatile("s_waitcnt vmcnt(4)" ::: "memory");
    BARR;
  }
#undef LDA
#undef LDB
#undef MFQ

  ushort* Cout = (SPLITK && kh2) ? C2 : C;
  const int addb = BIAS && !(SPLITK && kh2);
  const int r0 = (bm << 8) + wr * 128 + lg * 4;
  const int c0 = (bn << 8) + wc * 64 + lr;
#pragma unroll
  for (int m = 0; m < 8; m++) {
#pragma unroll
    for (int n = 0; n < 4; n++) {
      int col = c0 + n * 16;
      float bv = addb ? bias[col] : 0.0f;
      if (VSPLIT && col >= 2048) {
        int row = r0 + m * 16;
        int hh = (col - 2048) >> 6, e = col & 63;
        ushort4 uv;
        uv.x = f2b(acc[m][n][0]); uv.y = f2b(acc[m][n][1]);
        uv.z = f2b(acc[m][n][2]); uv.w = f2b(acc[m][n][3]);
        *(ushort4*)&C2[((((size_t)(row >> 10) * 16 + hh) * 64 + e) << 10) +
                       (row & 1023)] = uv;
      } else {
#pragma unroll
        for (int q = 0; q < 4; q++) {
          int row = r0 + m * 16 + q;
          float v = acc[m][n][q] + bv;
          if (RELU) v = fmaxf(v, 0.0f);
          if (VSPLIT)
            Cout[(size_t)row * 2048 + col] = f2b(v);
          else
            Cout[(size_t)row * N + col] = f2b(v);
        }
      }
    }
  }
}

// ---------------------------------------------------------------------------
// MFMA flash attention, QBLK=128 (2 q-tiles share each K/V tile load),
// KVBLK=128, length-sorted block remap. Q staged through Ks (49 KiB LDS).
// Swapped-QK^T lane-local softmax + T13 defer-max + T14 async-STAGE.
// ---------------------------------------------------------------------------
__global__ __launch_bounds__(256) void attention_mfma_k(
    const ushort* __restrict__ qk, const ushort* __restrict__ vT,
    const int* __restrict__ lens, ushort* __restrict__ concat) {
  __shared__ ushort Ks[128 * 64];      // K tile; Q (128 rows) staging first
  __shared__ ushort Vt[64 * 128];      // [d][key], 256B stride
  __shared__ ushort Pl[4][16 * 128];   // per-wave [qrow][key]
  const int blk = blockIdx.x;
  // length-sorted batch mapping: rank = blk>>7 (128 blocks per batch)
  int lv[8];
#pragma unroll
  for (int j = 0; j < 8; j++) lv[j] = lens[j];
  const int rank = blk >> 7;
  int b = 0;
#pragma unroll
  for (int cand = 0; cand < 8; cand++) {
    int r = 0;
#pragma unroll
    for (int j = 0; j < 8; j++)
      r += (lv[j] > lv[cand]) || (lv[j] == lv[cand] && j < cand);
    if (r == rank) b = cand;
  }
  const int h = (blk >> 3) & 15, q0 = (blk & 7) << 7;  // 128 q-rows
  const int t = threadIdx.x;
  const int lane = t & 63, w = t >> 6;
  const int lr = lane & 15, lg = lane >> 4;
  const int lg4 = lg * 4;
  const int len_b = lv[b];
  ushort* Plw = &Pl[w][0];
  const ushort* vbase = vT + ((size_t)(b * 16 + h) << 16);  // [64][1024]

  // stage 128 Q rows through Ks
#pragma unroll
  for (int i = 0; i < 8; i++) {
    int idx = t + i * 256;
    int r = idx >> 4, eq = idx & 15;
    const ushort* src =
        qk + ((size_t)(b * S_ + q0 + r)) * 2048 + h * 64 + eq * 4;
    *(ushort4*)swz_ptr(Ks, r, eq * 4) = *(const ushort4*)src;
  }
  __syncthreads();
  bf16x8 qfA[2], qfB[2];
#pragma unroll
  for (int ds = 0; ds < 2; ds++) {
    qfA[ds] = *(const bf16x8*)swz_ptr(Ks, w * 16 + lr, lg * 8 + ds * 32);
    qfB[ds] = *(const bf16x8*)swz_ptr(Ks, 64 + w * 16 + lr, lg * 8 + ds * 32);
  }

  float mA = -INFINITY, lA = 0.f, mB = -INFINITY, lB = 0.f;
  f32x4 oA[4] = {}, oB[4] = {};

  ushort4 kreg[8], vreg[8];
  auto LOADT = [&](int j0) {
#pragma unroll
    for (int i = 0; i < 8; i++) {
      int idx = t + i * 256;
      int kr = idx >> 4, keq = idx & 15;
      kreg[i] = *(const ushort4*)(qk + ((size_t)(b * S_ + j0 + kr)) * 2048 +
                                  1024 + h * 64 + keq * 4);
      int vr = idx >> 5, vc = idx & 31;
      vreg[i] = *(const ushort4*)(vbase + (size_t)vr * 1024 + j0 + vc * 4);
    }
  };

  // one q-tile pass: QK^T -> online softmax -> P -> PV
  auto PROC = [&](const bf16x8 (&qf)[2], float& mrun, float& lrun,
                  f32x4 (&o)[4], int j0) {
    f32x4 sacc[8];
    __builtin_amdgcn_s_setprio(1);
#pragma unroll
    for (int mb = 0; mb < 8; mb++) {
      sacc[mb] = (f32x4){0.f, 0.f, 0.f, 0.f};
#pragma unroll
      for (int ds = 0; ds < 2; ds++) {
        bf16x8 kf = *(const bf16x8*)swz_ptr(Ks, mb * 16 + lr, lg * 8 + ds * 32);
        sacc[mb] = __builtin_amdgcn_mfma_f32_16x16x32_bf16(kf, qf[ds], sacc[mb],
                                                           0, 0, 0);
      }
    }
    __builtin_amdgcn_s_setprio(0);

    float p[8][4];
    float pmax = -INFINITY;
#pragma unroll
    for (int mb = 0; mb < 8; mb++)
#pragma unroll
      for (int qi = 0; qi < 4; qi++) {
        float v = sacc[mb][qi] * 0.125f;
        if (j0 + mb * 16 + lg4 + qi >= len_b) v = NEG_;
        p[mb][qi] = v;
        pmax = fmaxf(pmax, v);
      }
    pmax = fmaxf(pmax, __shfl_xor(pmax, 16));
    pmax = fmaxf(pmax, __shfl_xor(pmax, 32));
    if (!__all(pmax - mrun <= 8.0f)) {  // T13 defer-max
      float mnew = fmaxf(mrun, pmax);
      float sc = __expf(mrun - mnew);
      mrun = mnew;
      lrun *= sc;
#pragma unroll
      for (int qi = 0; qi < 4; qi++) {
        float scq = __shfl(sc, (lg << 4) + lg4 + qi);
#pragma unroll
        for (int dt = 0; dt < 4; dt++) o[dt][qi] *= scq;
      }
    }
    float rs = 0.f;
#pragma unroll
    for (int mb = 0; mb < 8; mb++)
#pragma unroll
      for (int qi = 0; qi < 4; qi++) {
        float e = __expf(p[mb][qi] - mrun);
        p[mb][qi] = e;
        rs += e;
      }
    rs += __shfl_xor(rs, 16);
    rs += __shfl_xor(rs, 32);
    lrun += rs;

#pragma unroll
    for (int mb = 0; mb < 8; mb++) {
      ushort2 w0, w1;
      w0.x = f2b(p[mb][0]); w0.y = f2b(p[mb][1]);
      w1.x = f2b(p[mb][2]); w1.y = f2b(p[mb][3]);
      *(ushort2*)swz256(Plw, lr, mb * 16 + lg4) = w0;
      *(ushort2*)swz256(Plw, lr, mb * 16 + lg4 + 2) = w1;
    }

    bf16x8 pf[4];
#pragma unroll
    for (int ks = 0; ks < 4; ks++)
      pf[ks] = *(const bf16x8*)swz256(Plw, lr, lg * 8 + ks * 32);
    __builtin_amdgcn_s_setprio(1);
#pragma unroll
    for (int dt = 0; dt < 4; dt++) {
#pragma unroll
      for (int ks = 0; ks < 4; ks++) {
        bf16x8 vf =
            *(const bf16x8*)swz256(Vt, dt * 16 + lr, ks * 32 + lg * 8);
        o[dt] = __builtin_amdgcn_mfma_f32_16x16x32_bf16(pf[ks], vf, o[dt],
                                                        0, 0, 0);
      }
    }
    __builtin_amdgcn_s_setprio(0);
  };

  const int ntiles = (len_b + 127) >> 7;
  LOADT(0);
  for (int jt = 0; jt < ntiles; jt++) {
    const int j0 = jt << 7;
    __syncthreads();  // prev tile reads (and q-frag reads on iter 0) done
#pragma unroll
    for (int i = 0; i < 8; i++) {
      int idx = t + i * 256;
      int kr = idx >> 4, keq = idx & 15;
      *(ushort4*)swz_ptr(Ks, kr, keq * 4) = kreg[i];
      int vr = idx >> 5, vc = idx & 31;
      *(ushort4*)swz256(Vt, vr, vc * 4) = vreg[i];
    }
    if (jt + 1 < ntiles) LOADT(j0 + 128);
    __syncthreads();

    PROC(qfA, mA, lA, oA, j0);  // q rows [q0, q0+64)
    PROC(qfB, mB, lB, oB, j0);  // q rows [q0+64, q0+128)
  }

  // epilogue: both q-tiles
#pragma unroll
  for (int qi = 0; qi < 4; qi++) {
    float lqA = __shfl(lA, (lg << 4) + lg4 + qi);
    float invA = 1.0f / lqA;
    size_t rowA = (size_t)(b * S_ + q0 + w * 16 + lg4 + qi);
#pragma unroll
    for (int dt = 0; dt < 4; dt++)
      concat[rowA * 1024 + h * 64 + dt * 16 + lr] = f2b(oA[dt][qi] * invA);
    float lqB = __shfl(lB, (lg << 4) + lg4 + qi);
    float invB = 1.0f / lqB;
    size_t rowB = (size_t)(b * S_ + q0 + 64 + w * 16 + lg4 + qi);
#pragma unroll
    for (int dt = 0; dt < 4; dt++)
      concat[rowB * 1024 + h * 64 + dt * 16 + lr] = f2b(oB[dt][qi] * invB);
  }
}

// ---------------------------------------------------------------------------
// y = LayerNorm(a + r [+ r2]). a fp32 (ABF=0) or bf16 (ABF=1); r/r2 bf16.
// WY: write fp32 y. WBF: write bf16 yb.
// ---------------------------------------------------------------------------
template <int WY, int WBF, int TWO, int ABF>
__global__ __launch_bounds__(256) void add_ln_k(const void* __restrict__ a,
                                                const ushort* __restrict__ r,
                                                const ushort* __restrict__ r2,
                                                float* __restrict__ y,
                                                ushort* __restrict__ yb) {
  const int row = blockIdx.x, t = threadIdx.x;
  float v[4];
  if (ABF) {
    const ushort4 av = ((const ushort4*)((const ushort*)a + (size_t)row * 1024))[t];
    v[0] = b2f(av.x); v[1] = b2f(av.y); v[2] = b2f(av.z); v[3] = b2f(av.w);
  } else {
    const float4 av = ((const float4*)((const float*)a + (size_t)row * 1024))[t];
    v[0] = av.x; v[1] = av.y; v[2] = av.z; v[3] = av.w;
  }
  const ushort4 rv = ((const ushort4*)(r + (size_t)row * 1024))[t];
  v[0] += b2f(rv.x); v[1] += b2f(rv.y); v[2] += b2f(rv.z); v[3] += b2f(rv.w);
  if (TWO) {
    const ushort4 r2v = ((const ushort4*)(r2 + (size_t)row * 1024))[t];
    v[0] += b2f(r2v.x); v[1] += b2f(r2v.y);
    v[2] += b2f(r2v.z); v[3] += b2f(r2v.w);
  }
  float s = v[0] + v[1] + v[2] + v[3];
  float q = v[0] * v[0] + v[1] * v[1] + v[2] * v[2] + v[3] * v[3];
#pragma unroll
  for (int off = 1; off < 64; off <<= 1) {
    s += __shfl_xor(s, off);
    q += __shfl_xor(q, off);
  }
  __shared__ float ss[4], sq[4];
  int wave = t >> 6, lane = t & 63;
  if (lane == 0) { ss[wave] = s; sq[wave] = q; }
  __syncthreads();
  s = ss[0] + ss[1] + ss[2] + ss[3];
  q = sq[0] + sq[1] + sq[2] + sq[3];
  float mean = s * (1.f / 1024.f);
  float var = q * (1.f / 1024.f) - mean * mean;
  float inv = 1.0f / sqrtf(var + EPS_);
  float4 yo;
  yo.x = (v[0] - mean) * inv; yo.y = (v[1] - mean) * inv;
  yo.z = (v[2] - mean) * inv; yo.w = (v[3] - mean) * inv;
  if (WY) ((float4*)(y + (size_t)row * 1024))[t] = yo;
  if (WBF) {
    ushort4 ob;
    ob.x = f2b(yo.x); ob.y = f2b(yo.y); ob.z = f2b(yo.z); ob.w = f2b(yo.w);
    ((ushort4*)(yb + (size_t)row * 1024))[t] = ob;
  }
}

// ---------------------------------------------------------------------------
extern "C" void kernel_launch(void* const* d_in, const int* in_sizes, int n_in,
                              void* d_out, int out_size, void* d_ws, size_t ws_size,
                              hipStream_t stream) {
  const float* x  = (const float*)d_in[0];
  const int* len  = (const int*)d_in[1];
  const float* Wq = (const float*)d_in[2];
  const float* Wk = (const float*)d_in[3];
  const float* Wv = (const float*)d_in[4];
  const float* Wo = (const float*)d_in[5];
  const float* W1 = (const float*)d_in[6];
  const float* b1 = (const float*)d_in[7];
  const float* W2 = (const float*)d_in[8];
  const float* b2 = (const float*)d_in[9];
  float* out = (float*)d_out;

  if (ws_size < (size_t)184 * 1024 * 1024) return;
  char* w = (char*)d_ws;
  ushort* xbf    = (ushort*)(w);                        // 16MB
  ushort* qkvw   = (ushort*)(w + ((size_t)16 << 20));   // 6MB
  ushort* wob    = (ushort*)(w + ((size_t)22 << 20));   // 2MB
  ushort* w1b    = (ushort*)(w + ((size_t)24 << 20));   // 8MB
  ushort* w2b    = (ushort*)(w + ((size_t)32 << 20));   // 8MB
  ushort* qk2    = (ushort*)(w + ((size_t)40 << 20));   // 32MB  [8192][2048]
  ushort* vT     = (ushort*)(w + ((size_t)72 << 20));   // 16MB  [8][16][64][1024]
  ushort* concat = (ushort*)(w + ((size_t)88 << 20));   // 16MB
  ushort* parta  = (ushort*)(w + ((size_t)104 << 20));  // 16MB (split-K half 0)
  ushort* partb  = (ushort*)(w + ((size_t)120 << 20));  // 16MB (split-K half 1)
  ushort* x1b    = (ushort*)(w + ((size_t)168 << 20));  // 16MB (bf16 residual)
  ushort* hidden = (ushort*)(w + ((size_t)40 << 20));   // 64MB (reuse)

  prep_k<<<29696, 256, 0, stream>>>(x, Wq, Wk, Wv, Wo, W1, W2,
                                    xbf, qkvw, wob, w1b, w2b);

  // QKV projection (8-phase): Q,K -> qk2 (stride 2048), V -> vT
  gemm8p<0, 0, 1, 0><<<32 * 12, 512, 0, stream>>>(xbf, qkvw, nullptr, qk2,
                                                  vT, 8192, 3072, 1024);
  attention_mfma_k<<<1024, 256, 0, stream>>>(qk2, vT, len, concat);
  // output projection (8-phase, split-K=2) -> parta + partb
  gemm8p<0, 0, 0, 1><<<256, 512, 0, stream>>>(concat, wob, nullptr, parta,
                                              partb, 8192, 1024, 1024);
  // LN1: bf16 out only (x1b)
  add_ln_k<0, 1, 1, 0><<<8192, 256, 0, stream>>>(x, parta, partb, nullptr,
                                                 x1b);
  // FFN1 + bias + relu -> bf16 (8-phase, full K)
  gemm8p<1, 1, 0, 0><<<32 * 16, 512, 0, stream>>>(x1b, w1b, b1, hidden,
                                                  nullptr, 8192, 4096, 1024);
  // FFN2 (8-phase, split-K=2) + bias(half0) -> parta + partb
  gemm8p<1, 0, 0, 1><<<256, 512, 0, stream>>>(hidden, w2b, b2, parta,
                                              partb, 8192, 1024, 4096);
  // LN2: a = x1b (bf16), writes fp32 out
  add_ln_k<1, 0, 1, 1><<<8192, 256, 0, stream>>>(x1b, parta, partb, out,
                                                 nullptr);
}

// Round 22
// 357.613 us; speedup vs baseline: 1.0692x; 1.0692x over previous
//
#include <hip/hip_runtime.h>
#include <hip/hip_bf16.h>
#include <math.h>

#define B_ 8
#define S_ 1024
#define D_ 1024
#define H_ 16
#define DH_ 64
#define FFN_ 4096
#define NEG_ (-1e9f)
#define EPS_ 1e-5f

typedef float f32x4 __attribute__((ext_vector_type(4)));
typedef short bf16x8 __attribute__((ext_vector_type(8)));

__device__ __forceinline__ ushort f2b(float f) {
  __hip_bfloat16 h = __float2bfloat16(f);  // RNE
  return *reinterpret_cast<ushort*>(&h);
}
__device__ __forceinline__ float b2f(ushort u) {
  return __uint_as_float((unsigned)u << 16);
}

__device__ __forceinline__ void gload16(const void* g, void* l) {
  auto* lp = (__attribute__((address_space(3))) unsigned*)(uintptr_t)(l);
  __builtin_amdgcn_global_load_lds(
      (const __attribute__((address_space(1))) unsigned*)g, lp, 16, 0, 0);
}

// XOR swizzle for [*][64]-ushort LDS tiles (128B row stride)
__device__ __forceinline__ void* swz_ptr(void* base, int row, int col) {
  int byte = (row << 7) + (col << 1);
  byte ^= (row & 7) << 4;
  return (char*)base + byte;
}
// XOR swizzle for [*][128]-ushort LDS tiles (256B row stride)
__device__ __forceinline__ void* swz256(void* base, int row, int col) {
  int byte = (row << 8) + (col << 1);
  byte ^= (row & 7) << 4;
  return (char*)base + byte;
}

#define BARR asm volatile("s_barrier" ::: "memory")
#define LGKM0                                         \
  do {                                                \
    asm volatile("s_waitcnt lgkmcnt(0)" ::: "memory"); \
    __builtin_amdgcn_sched_barrier(0);                \
  } while (0)

// ---------------------------------------------------------------------------
// merged prep: cast x/Wo/W1/W2 to bf16 + pack qkv weights transposed.
// ---------------------------------------------------------------------------
__global__ __launch_bounds__(256) void prep_k(
    const float* __restrict__ x, const float* __restrict__ Wq,
    const float* __restrict__ Wk, const float* __restrict__ Wv,
    const float* __restrict__ Wo, const float* __restrict__ W1,
    const float* __restrict__ W2, ushort* __restrict__ xbf,
    ushort* __restrict__ qkvw, ushort* __restrict__ wob,
    ushort* __restrict__ w1b, ushort* __restrict__ w2b) {
  const int blk = blockIdx.x, t = threadIdx.x;
  if (blk < 8192) {  // x: 2M float4
    int i = blk * 256 + t;
    float4 v = ((const float4*)x)[i];
    ushort4 o;
    o.x = f2b(v.x); o.y = f2b(v.y); o.z = f2b(v.z); o.w = f2b(v.w);
    ((ushort4*)xbf)[i] = o;
  } else if (blk < 8192 + 12288) {  // qkvT pack: 3M scalars, k fastest
    int idx = (blk - 8192) * 256 + t;
    int k = idx & 1023, e = (idx >> 10) & 63;
    int h = (idx >> 16) & 15, which = idx >> 20;
    const float* W = (which == 0) ? Wq : (which == 1 ? Wk : Wv);
    float v = W[((size_t)h * D_ + k) * DH_ + e];
    qkvw[((size_t)which * 1024 + h * 64 + e) * 1024 + k] = f2b(v);
  } else if (blk < 8192 + 12288 + 1024) {  // Wo: 256K float4
    int i = (blk - 8192 - 12288) * 256 + t;
    float4 v = ((const float4*)Wo)[i];
    ushort4 o;
    o.x = f2b(v.x); o.y = f2b(v.y); o.z = f2b(v.z); o.w = f2b(v.w);
    ((ushort4*)wob)[i] = o;
  } else if (blk < 8192 + 12288 + 1024 + 4096) {  // W1: 1M float4
    int i = (blk - 8192 - 12288 - 1024) * 256 + t;
    float4 v = ((const float4*)W1)[i];
    ushort4 o;
    o.x = f2b(v.x); o.y = f2b(v.y); o.z = f2b(v.z); o.w = f2b(v.w);
    ((ushort4*)w1b)[i] = o;
  } else {  // W2: 1M float4
    int i = (blk - 8192 - 12288 - 1024 - 4096) * 256 + t;
    float4 v = ((const float4*)W2)[i];
    ushort4 o;
    o.x = f2b(v.x); o.y = f2b(v.y); o.z = f2b(v.z); o.w = f2b(v.w);
    ((ushort4*)w2b)[i] = o;
  }
}

// ---------------------------------------------------------------------------
// 8-phase 256x256 bf16 MFMA GEMM (T2+T3+T4+T5), K-half staging (R14-proven).
// SPLITK=1: block-half kh2 -> C / C2. VSPLIT (QKV): C2 slot is vT.
// ---------------------------------------------------------------------------
template <int BIAS, int RELU, int VSPLIT, int SPLITK>
__global__ __launch_bounds__(512, 2) void gemm8p(
    const ushort* __restrict__ A, const ushort* __restrict__ Bt,
    const float* __restrict__ bias, ushort* __restrict__ C,
    ushort* __restrict__ C2, int M, int N, int K) {
  __shared__ ushort lds[2][2][2][256 * 32];  // [buf][A/B][kh][row][k] 128KiB
  int bid = blockIdx.x;
  int nwg = gridDim.x;
  int kh2 = 0;
  if (SPLITK) {
    int hw = nwg >> 1;
    if (bid >= hw) { kh2 = 1; bid -= hw; }
    nwg = hw;
  }
  const int nbn = N >> 8;
  const int cpx = nwg >> 3;
  const int swz = (bid & 7) * cpx + (bid >> 3);  // XCD swizzle (nwg%8==0)
  const int bm = swz / nbn, bn = swz % nbn;
  const int Keff = SPLITK ? (K >> 1) : K;

  const int t = threadIdx.x;
  const int lane = t & 63, lr = lane & 15, lg = lane >> 4;
  const int wid = t >> 6, wr = wid >> 2, wc = wid & 3;  // 2M x 4N
  const size_t Kb = (size_t)K * 2;  // full row stride
  const char* Ab = (const char*)A + ((size_t)(bm << 8)) * Kb +
                   (size_t)kh2 * Keff * 2;
  const char* Bb = (const char*)Bt + ((size_t)(bn << 8)) * Kb +
                   (size_t)kh2 * Keff * 2;
  const int NT = Keff >> 6;
  const int niter = NT >> 1;

  const int g0row = t >> 2;
  const int gsi = (t & 3) ^ ((g0row >> 2) & 3);  // pre-swizzled src granule
  auto STG = [&](int mat, int kh, int kt) {
    char* base = (char*)&lds[kt & 1][mat][kh][0];
    const char* gsrc = mat ? Bb : Ab;
#pragma unroll
    for (int j = 0; j < 2; j++) {
      int row = g0row + j * 128;
      const char* src = gsrc + (size_t)row * Kb +
                        (size_t)(kt * 64 + kh * 32) * 2 + gsi * 16;
      gload16(src, base + t * 16 + j * 8192);
    }
  };

  const int rg = (lg ^ ((lr >> 2) & 3)) << 3;  // swizzled k-granule (ushort)
#define LDA(DST, BUF, KH, QM)                                            \
  _Pragma("unroll") for (int mm = 0; mm < 4; mm++) {                     \
    int row = wr * 128 + (QM)*64 + mm * 16 + lr;                         \
    DST[mm] = *(const bf16x8*)&lds[BUF][0][KH][row * 32 + rg];           \
  }
#define LDB(DST, BUF, KH)                                                \
  _Pragma("unroll") for (int nn = 0; nn < 4; nn++) {                     \
    int row = wc * 64 + nn * 16 + lr;                                    \
    DST[nn] = *(const bf16x8*)&lds[BUF][1][KH][row * 32 + rg];           \
  }
#define MFQ(QM, AS, BS)                                                  \
  do {                                                                   \
    __builtin_amdgcn_s_setprio(1);                                       \
    _Pragma("unroll") for (int mm = 0; mm < 4; mm++)                     \
        _Pragma("unroll") for (int nn = 0; nn < 4; nn++)                 \
            acc[(QM)*4 + mm][nn] = __builtin_amdgcn_mfma_f32_16x16x32_bf16( \
                AS[mm], BS[nn], acc[(QM)*4 + mm][nn], 0, 0, 0);          \
    __builtin_amdgcn_s_setprio(0);                                       \
  } while (0)

  f32x4 acc[8][4] = {};
  bf16x8 aS0[4], aS1[4], bS0[4], bS1[4];

  STG(0, 0, 0); STG(1, 0, 0); STG(0, 1, 0); STG(1, 1, 0);
  STG(0, 0, 1); STG(1, 0, 1);
  asm volatile("s_waitcnt vmcnt(4)" ::: "memory");
  BARR;

  for (int i = 0; i < niter; i++) {
    const int c1 = 2 * i + 1, c2 = 2 * i + 2, c3 = 2 * i + 3;
    LDA(aS0, 0, 0, 0); LDB(bS0, 0, 0); STG(0, 1, c1);
    BARR; LGKM0; MFQ(0, aS0, bS0); BARR;
    LDA(aS1, 0, 0, 1); STG(1, 1, c1);
    BARR; LGKM0; MFQ(1, aS1, bS0); BARR;
    LDA(aS0, 0, 1, 0); LDB(bS1, 0, 1);
    if (c2 < NT) STG(0, 0, c2);
    BARR; LGKM0; MFQ(0, aS0, bS1); BARR;
    LDA(aS1, 0, 1, 1);
    if (c2 < NT) STG(1, 0, c2);
    BARR; LGKM0; MFQ(1, aS1, bS1);
    if (i + 1 < niter)
      asm volatile("s_waitcnt vmcnt(4)" ::: "memory");
    else
      asm volatile("s_waitcnt vmcnt(0)" ::: "memory");
    BARR;
    LDA(aS0, 1, 0, 0); LDB(bS0, 1, 0);
    if (c2 < NT) STG(0, 1, c2);
    BARR; LGKM0; MFQ(0, aS0, bS0); BARR;
    LDA(aS1, 1, 0, 1);
    if (c2 < NT) STG(1, 1, c2);
    BARR; LGKM0; MFQ(1, aS1, bS0); BARR;
    LDA(aS0, 1, 1, 0); LDB(bS1, 1, 1);
    if (c3 < NT) STG(0, 0, c3);
    BARR; LGKM0; MFQ(0, aS0, bS1); BARR;
    LDA(aS1, 1, 1, 1);
    if (c3 < NT) STG(1, 0, c3);
    BARR; LGKM0; MFQ(1, aS1, bS1);
    asm volatile("s_waitcnt vmcnt(4)" ::: "memory");
    BARR;
  }
#undef LDA
#undef LDB
#undef MFQ

  ushort* Cout = (SPLITK && kh2) ? C2 : C;
  const int addb = BIAS && !(SPLITK && kh2);
  const int r0 = (bm << 8) + wr * 128 + lg * 4;
  const int c0 = (bn << 8) + wc * 64 + lr;
#pragma unroll
  for (int m = 0; m < 8; m++) {
#pragma unroll
    for (int n = 0; n < 4; n++) {
      int col = c0 + n * 16;
      float bv = addb ? bias[col] : 0.0f;
      if (VSPLIT && col >= 2048) {
        int row = r0 + m * 16;
        int hh = (col - 2048) >> 6, e = col & 63;
        ushort4 uv;
        uv.x = f2b(acc[m][n][0]); uv.y = f2b(acc[m][n][1]);
        uv.z = f2b(acc[m][n][2]); uv.w = f2b(acc[m][n][3]);
        *(ushort4*)&C2[((((size_t)(row >> 10) * 16 + hh) * 64 + e) << 10) +
                       (row & 1023)] = uv;
      } else {
#pragma unroll
        for (int q = 0; q < 4; q++) {
          int row = r0 + m * 16 + q;
          float v = acc[m][n][q] + bv;
          if (RELU) v = fmaxf(v, 0.0f);
          if (VSPLIT)
            Cout[(size_t)row * 2048 + col] = f2b(v);
          else
            Cout[(size_t)row * N + col] = f2b(v);
        }
      }
    }
  }
}

// ---------------------------------------------------------------------------
// MFMA flash attention (R16 body), KVBLK=128, + length-sorted block remap.
// ---------------------------------------------------------------------------
__global__ __launch_bounds__(256) void attention_mfma_k(
    const ushort* __restrict__ qk, const ushort* __restrict__ vT,
    const int* __restrict__ lens, ushort* __restrict__ concat) {
  __shared__ ushort Qs[64 * 64];       // [qrow][d], 128B stride
  __shared__ ushort Ks[128 * 64];      // [key][d], 128B stride
  __shared__ ushort Vt[64 * 128];      // [d][key], 256B stride
  __shared__ ushort Pl[4][16 * 128];   // per-wave [qrow][key], 256B stride
  const int blk = blockIdx.x;
  // length-sorted batch mapping: rank in descending len, ties by index
  int lv[8];
#pragma unroll
  for (int j = 0; j < 8; j++) lv[j] = lens[j];
  const int rank = blk >> 8;
  int b = 0;
#pragma unroll
  for (int cand = 0; cand < 8; cand++) {
    int r = 0;
#pragma unroll
    for (int j = 0; j < 8; j++)
      r += (lv[j] > lv[cand]) || (lv[j] == lv[cand] && j < cand);
    if (r == rank) b = cand;
  }
  const int h = (blk >> 4) & 15, q0 = (blk & 15) << 6;
  const int t = threadIdx.x;
  const int lane = t & 63, w = t >> 6;
  const int lr = lane & 15, lg = lane >> 4;
  const int lg4 = lg * 4;
  const int len_b = lv[b];
  ushort* Plw = &Pl[w][0];
  const ushort* vbase = vT + ((size_t)(b * 16 + h) << 16);  // [64][1024]

#pragma unroll
  for (int i = 0; i < 4; i++) {
    int idx = t + i * 256;
    int r = idx >> 4, eq = idx & 15;
    const ushort* src =
        qk + ((size_t)(b * S_ + q0 + r)) * 2048 + h * 64 + eq * 4;
    *(ushort4*)swz_ptr(Qs, r, eq * 4) = *(const ushort4*)src;
  }
  __syncthreads();
  bf16x8 qf[2];
#pragma unroll
  for (int ds = 0; ds < 2; ds++)
    qf[ds] = *(const bf16x8*)swz_ptr(Qs, w * 16 + lr, lg * 8 + ds * 32);

  float mrun = -INFINITY, lrun = 0.f;
  f32x4 o[4] = {};

  ushort4 kreg[8], vreg[8];
  auto LOADT = [&](int j0) {
#pragma unroll
    for (int i = 0; i < 8; i++) {
      int idx = t + i * 256;
      int kr = idx >> 4, keq = idx & 15;
      kreg[i] = *(const ushort4*)(qk + ((size_t)(b * S_ + j0 + kr)) * 2048 +
                                  1024 + h * 64 + keq * 4);
      int vr = idx >> 5, vc = idx & 31;
      vreg[i] = *(const ushort4*)(vbase + (size_t)vr * 1024 + j0 + vc * 4);
    }
  };

  const int ntiles = (len_b + 127) >> 7;
  LOADT(0);
  for (int jt = 0; jt < ntiles; jt++) {
    const int j0 = jt << 7;
    __syncthreads();
#pragma unroll
    for (int i = 0; i < 8; i++) {
      int idx = t + i * 256;
      int kr = idx >> 4, keq = idx & 15;
      *(ushort4*)swz_ptr(Ks, kr, keq * 4) = kreg[i];
      int vr = idx >> 5, vc = idx & 31;
      *(ushort4*)swz256(Vt, vr, vc * 4) = vreg[i];
    }
    if (jt + 1 < ntiles) LOADT(j0 + 128);
    __syncthreads();

    f32x4 sacc[8];
    __builtin_amdgcn_s_setprio(1);
#pragma unroll
    for (int mb = 0; mb < 8; mb++) {
      sacc[mb] = (f32x4){0.f, 0.f, 0.f, 0.f};
#pragma unroll
      for (int ds = 0; ds < 2; ds++) {
        bf16x8 kf = *(const bf16x8*)swz_ptr(Ks, mb * 16 + lr, lg * 8 + ds * 32);
        sacc[mb] = __builtin_amdgcn_mfma_f32_16x16x32_bf16(kf, qf[ds], sacc[mb],
                                                           0, 0, 0);
      }
    }
    __builtin_amdgcn_s_setprio(0);

    float p[8][4];
    float pmax = -INFINITY;
#pragma unroll
    for (int mb = 0; mb < 8; mb++)
#pragma unroll
      for (int qi = 0; qi < 4; qi++) {
        float v = sacc[mb][qi] * 0.125f;
        if (j0 + mb * 16 + lg4 + qi >= len_b) v = NEG_;
        p[mb][qi] = v;
        pmax = fmaxf(pmax, v);
      }
    pmax = fmaxf(pmax, __shfl_xor(pmax, 16));
    pmax = fmaxf(pmax, __shfl_xor(pmax, 32));
    if (!__all(pmax - mrun <= 8.0f)) {  // T13 defer-max
      float mnew = fmaxf(mrun, pmax);
      float sc = __expf(mrun - mnew);
      mrun = mnew;
      lrun *= sc;
#pragma unroll
      for (int qi = 0; qi < 4; qi++) {
        float scq = __shfl(sc, (lg << 4) + lg4 + qi);
#pragma unroll
        for (int dt = 0; dt < 4; dt++) o[dt][qi] *= scq;
      }
    }
    float rs = 0.f;
#pragma unroll
    for (int mb = 0; mb < 8; mb++)
#pragma unroll
      for (int qi = 0; qi < 4; qi++) {
        float e = __expf(p[mb][qi] - mrun);
        p[mb][qi] = e;
        rs += e;
      }
    rs += __shfl_xor(rs, 16);
    rs += __shfl_xor(rs, 32);
    lrun += rs;

#pragma unroll
    for (int mb = 0; mb < 8; mb++) {
      ushort2 w0, w1;
      w0.x = f2b(p[mb][0]); w0.y = f2b(p[mb][1]);
      w1.x = f2b(p[mb][2]); w1.y = f2b(p[mb][3]);
      *(ushort2*)swz256(Plw, lr, mb * 16 + lg4) = w0;
      *(ushort2*)swz256(Plw, lr, mb * 16 + lg4 + 2) = w1;
    }

    bf16x8 pf[4];
#pragma unroll
    for (int ks = 0; ks < 4; ks++)
      pf[ks] = *(const bf16x8*)swz256(Plw, lr, lg * 8 + ks * 32);
    __builtin_amdgcn_s_setprio(1);
#pragma unroll
    for (int dt = 0; dt < 4; dt++) {
#pragma unroll
      for (int ks = 0; ks < 4; ks++) {
        bf16x8 vf =
            *(const bf16x8*)swz256(Vt, dt * 16 + lr, ks * 32 + lg * 8);
        o[dt] = __builtin_amdgcn_mfma_f32_16x16x32_bf16(pf[ks], vf, o[dt],
                                                        0, 0, 0);
      }
    }
    __builtin_amdgcn_s_setprio(0);
  }

#pragma unroll
  for (int qi = 0; qi < 4; qi++) {
    float lq = __shfl(lrun, (lg << 4) + lg4 + qi);
    float inv = 1.0f / lq;
    size_t row = (size_t)(b * S_ + q0 + w * 16 + lg4 + qi);
#pragma unroll
    for (int dt = 0; dt < 4; dt++)
      concat[row * 1024 + h * 64 + dt * 16 + lr] = f2b(o[dt][qi] * inv);
  }
}

// ---------------------------------------------------------------------------
// y = LayerNorm(a + r [+ r2]). a fp32 (ABF=0) or bf16 (ABF=1); r/r2 bf16.
// WY: write fp32 y. WBF: write bf16 yb.
// ---------------------------------------------------------------------------
template <int WY, int WBF, int TWO, int ABF>
__global__ __launch_bounds__(256) void add_ln_k(const void* __restrict__ a,
                                                const ushort* __restrict__ r,
                                                const ushort* __restrict__ r2,
                                                float* __restrict__ y,
                                                ushort* __restrict__ yb) {
  const int row = blockIdx.x, t = threadIdx.x;
  float v[4];
  if (ABF) {
    const ushort4 av = ((const ushort4*)((const ushort*)a + (size_t)row * 1024))[t];
    v[0] = b2f(av.x); v[1] = b2f(av.y); v[2] = b2f(av.z); v[3] = b2f(av.w);
  } else {
    const float4 av = ((const float4*)((const float*)a + (size_t)row * 1024))[t];
    v[0] = av.x; v[1] = av.y; v[2] = av.z; v[3] = av.w;
  }
  const ushort4 rv = ((const ushort4*)(r + (size_t)row * 1024))[t];
  v[0] += b2f(rv.x); v[1] += b2f(rv.y); v[2] += b2f(rv.z); v[3] += b2f(rv.w);
  if (TWO) {
    const ushort4 r2v = ((const ushort4*)(r2 + (size_t)row * 1024))[t];
    v[0] += b2f(r2v.x); v[1] += b2f(r2v.y);
    v[2] += b2f(r2v.z); v[3] += b2f(r2v.w);
  }
  float s = v[0] + v[1] + v[2] + v[3];
  float q = v[0] * v[0] + v[1] * v[1] + v[2] * v[2] + v[3] * v[3];
#pragma unroll
  for (int off = 1; off < 64; off <<= 1) {
    s += __shfl_xor(s, off);
    q += __shfl_xor(q, off);
  }
  __shared__ float ss[4], sq[4];
  int wave = t >> 6, lane = t & 63;
  if (lane == 0) { ss[wave] = s; sq[wave] = q; }
  __syncthreads();
  s = ss[0] + ss[1] + ss[2] + ss[3];
  q = sq[0] + sq[1] + sq[2] + sq[3];
  float mean = s * (1.f / 1024.f);
  float var = q * (1.f / 1024.f) - mean * mean;
  float inv = 1.0f / sqrtf(var + EPS_);
  float4 yo;
  yo.x = (v[0] - mean) * inv; yo.y = (v[1] - mean) * inv;
  yo.z = (v[2] - mean) * inv; yo.w = (v[3] - mean) * inv;
  if (WY) ((float4*)(y + (size_t)row * 1024))[t] = yo;
  if (WBF) {
    ushort4 ob;
    ob.x = f2b(yo.x); ob.y = f2b(yo.y); ob.z = f2b(yo.z); ob.w = f2b(yo.w);
    ((ushort4*)(yb + (size_t)row * 1024))[t] = ob;
  }
}

// ---------------------------------------------------------------------------
extern "C" void kernel_launch(void* const* d_in, const int* in_sizes, int n_in,
                              void* d_out, int out_size, void* d_ws, size_t ws_size,
                              hipStream_t stream) {
  const float* x  = (const float*)d_in[0];
  const int* len  = (const int*)d_in[1];
  const float* Wq = (const float*)d_in[2];
  const float* Wk = (const float*)d_in[3];
  const float* Wv = (const float*)d_in[4];
  const float* Wo = (const float*)d_in[5];
  const float* W1 = (const float*)d_in[6];
  const float* b1 = (const float*)d_in[7];
  const float* W2 = (const float*)d_in[8];
  const float* b2 = (const float*)d_in[9];
  float* out = (float*)d_out;

  if (ws_size < (size_t)184 * 1024 * 1024) return;
  char* w = (char*)d_ws;
  ushort* xbf    = (ushort*)(w);                        // 16MB
  ushort* qkvw   = (ushort*)(w + ((size_t)16 << 20));   // 6MB
  ushort* wob    = (ushort*)(w + ((size_t)22 << 20));   // 2MB
  ushort* w1b    = (ushort*)(w + ((size_t)24 << 20));   // 8MB
  ushort* w2b    = (ushort*)(w + ((size_t)32 << 20));   // 8MB
  ushort* qk2    = (ushort*)(w + ((size_t)40 << 20));   // 32MB  [8192][2048]
  ushort* vT     = (ushort*)(w + ((size_t)72 << 20));   // 16MB  [8][16][64][1024]
  ushort* concat = (ushort*)(w + ((size_t)88 << 20));   // 16MB
  ushort* parta  = (ushort*)(w + ((size_t)104 << 20));  // 16MB (split-K half 0)
  ushort* partb  = (ushort*)(w + ((size_t)120 << 20));  // 16MB (split-K half 1)
  ushort* x1b    = (ushort*)(w + ((size_t)168 << 20));  // 16MB (bf16 residual)
  ushort* hidden = (ushort*)(w + ((size_t)40 << 20));   // 64MB (reuse)

  prep_k<<<29696, 256, 0, stream>>>(x, Wq, Wk, Wv, Wo, W1, W2,
                                    xbf, qkvw, wob, w1b, w2b);

  // QKV projection (8-phase): Q,K -> qk2 (stride 2048), V -> vT
  gemm8p<0, 0, 1, 0><<<32 * 12, 512, 0, stream>>>(xbf, qkvw, nullptr, qk2,
                                                  vT, 8192, 3072, 1024);
  attention_mfma_k<<<2048, 256, 0, stream>>>(qk2, vT, len, concat);
  // output projection (8-phase, split-K=2) -> parta + partb
  gemm8p<0, 0, 0, 1><<<256, 512, 0, stream>>>(concat, wob, nullptr, parta,
                                              partb, 8192, 1024, 1024);
  // LN1: bf16 out only (x1b)
  add_ln_k<0, 1, 1, 0><<<8192, 256, 0, stream>>>(x, parta, partb, nullptr,
                                                 x1b);
  // FFN1 + bias + relu -> bf16 (8-phase, full K)
  gemm8p<1, 1, 0, 0><<<32 * 16, 512, 0, stream>>>(x1b, w1b, b1, hidden,
                                                  nullptr, 8192, 4096, 1024);
  // FFN2 (8-phase, split-K=2) + bias(half0) -> parta + partb
  gemm8p<1, 0, 0, 1><<<256, 512, 0, stream>>>(hidden, w2b, b2, parta,
                                              partb, 8192, 1024, 4096);
  // LN2: a = x1b (bf16), writes fp32 out
  add_ln_k<1, 0, 1, 1><<<8192, 256, 0, stream>>>(x1b, parta, partb, out,
                                                 nullptr);
}